// Round 14
// baseline (539.394 us; speedup 1.0000x reference)
//
#include <hip/hip_runtime.h>
#include <hip/hip_bf16.h>
#include <float.h>

// Problem constants: B=16, M=4096.
#define NB 16
#define MPTS 4096
#define NPRED (NB * MPTS)       // 65536 pred points
#define GTQ 16                  // gt sixteenths (one per block)
#define GTN 256                 // gt points per block
#define NT 8                    // MFMA tiles of 32 gt each per block
#define BLK 256                 // 4 waves
#define FRAGS 4                 // B-fragments (preds) per wave: 4*32 = 128
#define PREDS_PER_BLK 512       // 4 waves * 128
#define PGRP 8                  // pred groups per batch (4096/512)

typedef _Float16 half8 __attribute__((ext_vector_type(8)));
typedef float f32x16 __attribute__((ext_vector_type(16)));

// Split x into f16 hi + f16 lo (x ~= hi + lo).
__device__ inline void split16(float x, _Float16& hi, _Float16& lo) {
    hi = (_Float16)x;
    lo = (_Float16)(x - (float)hi);
}

// Main kernel (R11 structure, GTQ=16): one block = (b, 512-pred group, gtq).
// S[gt][pred] = gn - 2 p.g via mfma_f32_32x32x16_f16 with hi/lo split K-slots:
//  A kh0: [hux,huy,huz,hux,huy,huz,lux,luy]  A kh1: [luz,gnh,gnl,0,0,0,0,0]
//  B kh0: [hpx,hpy,hpz,lpx,lpy,lpz,hpx,hpy]  B kh1: [hpz,1,1,0,0,0,0,0]
// 8 KB LDS, ~56 VGPR, launch_bounds(256,8) -> 8 blocks/CU (8 waves/SIMD).
__global__ __launch_bounds__(BLK, 8) void adds_mfma(
    const float* __restrict__ pred_R, const float* __restrict__ pred_t,
    const float* __restrict__ gt_R,   const float* __restrict__ gt_t,
    const float* __restrict__ mp,     float* __restrict__ pmin,
    float* __restrict__ out)
{
    __shared__ half8 aT[NT * 64];        // 8 KB, [tile][vlane]

    const int bid = blockIdx.x;
    const int gtq = bid & (GTQ - 1);
    const int pg  = (bid >> 4) & (PGRP - 1);
    const int b   = bid >> 7;
    const int tid = threadIdx.x;
    const int ln  = tid & 63;
    const int wv  = tid >> 6;

    if (bid == 0 && tid == 0) out[0] = 0.0f;   // re-zero every call (replay-safe)

    // ---- stage A tiles: 256 points, one transform per point, 2 entries ----
    {
        float gR[9];
#pragma unroll
        for (int i = 0; i < 9; ++i) gR[i] = gt_R[b * 9 + i];
        const float gtx = gt_t[b * 3 + 0];
        const float gty = gt_t[b * 3 + 1];
        const float gtz = gt_t[b * 3 + 2];

        const int nl = tid;                        // GTN == BLK
        const int n  = gtq * GTN + nl;
        const float mx = mp[n * 3 + 0];
        const float my = mp[n * 3 + 1];
        const float mz = mp[n * 3 + 2];
        const float gx = fmaf(gR[0], mx, fmaf(gR[1], my, fmaf(gR[2], mz, gtx)));
        const float gy = fmaf(gR[3], mx, fmaf(gR[4], my, fmaf(gR[5], mz, gty)));
        const float gz = fmaf(gR[6], mx, fmaf(gR[7], my, fmaf(gR[8], mz, gtz)));
        const float gn = fmaf(gx, gx, fmaf(gy, gy, gz * gz));
        const float ux = -2.0f * gx, uy = -2.0f * gy, uz = -2.0f * gz;
        _Float16 hux, lux, huy, luy, huz, luz, gnh, gnl;
        split16(ux, hux, lux);
        split16(uy, huy, luy);
        split16(uz, huz, luz);
        split16(gn, gnh, gnl);
        half8 k0, k1;
        k0[0] = hux; k0[1] = huy; k0[2] = huz;
        k0[3] = hux; k0[4] = huy; k0[5] = huz;
        k0[6] = lux; k0[7] = luy;
        k1[0] = luz; k1[1] = gnh; k1[2] = gnl;
        k1[3] = (_Float16)0.0f; k1[4] = (_Float16)0.0f; k1[5] = (_Float16)0.0f;
        k1[6] = (_Float16)0.0f; k1[7] = (_Float16)0.0f;
        const int t = nl >> 5, r = nl & 31;
        aT[t * 64 + r]      = k0;
        aT[t * 64 + 32 + r] = k1;
    }

    // ---- B-fragments (pred side), constant across tiles ----
    float pR[9];
#pragma unroll
    for (int i = 0; i < 9; ++i) pR[i] = pred_R[b * 9 + i];
    const float ptx = pred_t[b * 3 + 0];
    const float pty = pred_t[b * 3 + 1];
    const float ptz = pred_t[b * 3 + 2];

    half8 bf[FRAGS];
    float pn[FRAGS];
    const int kh = ln >> 5;
#pragma unroll
    for (int f = 0; f < FRAGS; ++f) {
        const int predl = pg * PREDS_PER_BLK + wv * 128 + f * 32 + (ln & 31);
        const float mx = mp[predl * 3 + 0];
        const float my = mp[predl * 3 + 1];
        const float mz = mp[predl * 3 + 2];
        const float px = fmaf(pR[0], mx, fmaf(pR[1], my, fmaf(pR[2], mz, ptx)));
        const float py = fmaf(pR[3], mx, fmaf(pR[4], my, fmaf(pR[5], mz, pty)));
        const float pz = fmaf(pR[6], mx, fmaf(pR[7], my, fmaf(pR[8], mz, ptz)));
        pn[f] = fmaf(px, px, fmaf(py, py, pz * pz));
        _Float16 hpx, lpx, hpy, lpy, hpz, lpz;
        split16(px, hpx, lpx);
        split16(py, hpy, lpy);
        split16(pz, hpz, lpz);
        half8 v;
        if (kh == 0) {
            v[0] = hpx; v[1] = hpy; v[2] = hpz;
            v[3] = lpx; v[4] = lpy; v[5] = lpz;
            v[6] = hpx; v[7] = hpy;
        } else {
            v[0] = hpz; v[1] = (_Float16)1.0f; v[2] = (_Float16)1.0f;
            v[3] = (_Float16)0.0f; v[4] = (_Float16)0.0f;
            v[5] = (_Float16)0.0f; v[6] = (_Float16)0.0f;
            v[7] = (_Float16)0.0f;
        }
        bf[f] = v;
    }

    __syncthreads();

    // ---- MFMA loop over 8 gt tiles (2+2 MFMA groups) ----
    f32x16 zc;
#pragma unroll
    for (int i = 0; i < 16; ++i) zc[i] = 0.0f;

    float best[FRAGS][8];
#pragma unroll
    for (int f = 0; f < FRAGS; ++f)
#pragma unroll
        for (int j = 0; j < 8; ++j) best[f][j] = FLT_MAX;

    half8 a_cur = aT[ln];
    for (int t = 0; t < NT; ++t) {
        const half8 a_nxt = (t + 1 < NT) ? aT[(t + 1) * 64 + ln] : a_cur;
        {
            const f32x16 d0 = __builtin_amdgcn_mfma_f32_32x32x16_f16(a_cur, bf[0], zc, 0, 0, 0);
            const f32x16 d1 = __builtin_amdgcn_mfma_f32_32x32x16_f16(a_cur, bf[1], zc, 0, 0, 0);
#pragma unroll
            for (int j = 0; j < 8; ++j) {
                best[0][j] = fminf(best[0][j], fminf(d0[2 * j], d0[2 * j + 1]));
                best[1][j] = fminf(best[1][j], fminf(d1[2 * j], d1[2 * j + 1]));
            }
        }
        {
            const f32x16 d2 = __builtin_amdgcn_mfma_f32_32x32x16_f16(a_cur, bf[2], zc, 0, 0, 0);
            const f32x16 d3 = __builtin_amdgcn_mfma_f32_32x32x16_f16(a_cur, bf[3], zc, 0, 0, 0);
#pragma unroll
            for (int j = 0; j < 8; ++j) {
                best[2][j] = fminf(best[2][j], fminf(d2[2 * j], d2[2 * j + 1]));
                best[3][j] = fminf(best[3][j], fminf(d3[2 * j], d3[2 * j + 1]));
            }
        }
        a_cur = a_nxt;
    }

    // ---- epilogue: fold 8 regs, merge lane halves, add pn, store ----
#pragma unroll
    for (int f = 0; f < FRAGS; ++f) {
        float r = fminf(fminf(fminf(best[f][0], best[f][1]), fminf(best[f][2], best[f][3])),
                        fminf(fminf(best[f][4], best[f][5]), fminf(best[f][6], best[f][7])));
        r = fminf(r, __shfl_xor(r, 32, 64));
        const float d2v = fmaxf(pn[f] + r, 0.0f);
        if (ln < 32) {
            const int predl = pg * PREDS_PER_BLK + wv * 128 + f * 32 + ln;
            pmin[gtq * NPRED + b * MPTS + predl] = d2v;
        }
    }
}

// Finish: per pred point min over the 16 partials -> sqrt -> block sum ->
// atomicAdd of the scaled partial into out[0] (zeroed by adds_mfma).
__global__ __launch_bounds__(512) void adds_finish(
    const float* __restrict__ pmin, float* __restrict__ out)
{
    __shared__ float wsum[8];
    const int tid = threadIdx.x;
    const int g = blockIdx.x * 512 + tid;
    float m0 = FLT_MAX, m1 = FLT_MAX;
#pragma unroll
    for (int q = 0; q < GTQ; q += 2) {
        m0 = fminf(m0, pmin[(q + 0) * NPRED + g]);
        m1 = fminf(m1, pmin[(q + 1) * NPRED + g]);
    }
    float s = sqrtf(fminf(m0, m1));
#pragma unroll
    for (int off = 32; off > 0; off >>= 1) s += __shfl_down(s, off, 64);
    if ((tid & 63) == 0) wsum[tid >> 6] = s;
    __syncthreads();
    if (tid == 0) {
        float t = 0.0f;
#pragma unroll
        for (int w = 0; w < 8; ++w) t += wsum[w];
        atomicAdd(out, t * (1.0f / (float)NPRED));
    }
}

extern "C" void kernel_launch(void* const* d_in, const int* in_sizes, int n_in,
                              void* d_out, int out_size, void* d_ws, size_t ws_size,
                              hipStream_t stream) {
    const float* pred_R = (const float*)d_in[0];
    const float* pred_t = (const float*)d_in[1];
    const float* gt_R   = (const float*)d_in[2];
    const float* gt_t   = (const float*)d_in[3];
    const float* mp     = (const float*)d_in[4];
    float* out = (float*)d_out;
    float* pmin = (float*)d_ws;                 // 16*64K*4 = 4 MB

    // grid: b(16) x pred-group(8) x gtq(16) = 2048 blocks (8 blocks/CU)
    adds_mfma<<<dim3(NB * PGRP * GTQ), dim3(BLK), 0, stream>>>(
        pred_R, pred_t, gt_R, gt_t, mp, pmin, out);
    adds_finish<<<dim3(NPRED / 512), dim3(512), 0, stream>>>(pmin, out);
}

// Round 15
// 18.259 us; speedup vs baseline: 29.5416x; 29.5416x over previous
//
#include <hip/hip_runtime.h>
#include <hip/hip_bf16.h>
#include <float.h>

// Problem constants: B=16, M=4096.
#define NB 16
#define MPTS 4096
#define NPRED (NB * MPTS)       // 65536 pred points
#define GTQ 8                   // gt eighths (one per block)
#define GTN 512                 // gt points per block
#define NT 16                   // MFMA tiles of 32 gt each per block
#define BLK 256                 // 4 waves
#define FRAGS 4                 // B-fragments (preds) per wave: 4*32 = 128
#define PREDS_PER_BLK 512       // 4 waves * 128
#define PGRP 8                  // pred groups per batch (4096/512)

typedef _Float16 half8 __attribute__((ext_vector_type(8)));
typedef float f32x16 __attribute__((ext_vector_type(16)));

// Split x into f16 hi + f16 lo (x ~= hi + lo).
__device__ inline void split16(float x, _Float16& hi, _Float16& lo) {
    hi = (_Float16)x;
    lo = (_Float16)(x - (float)hi);
}

// Main kernel (R11-proven, 20.1us config): one block = (b, 512-pred group, gtq).
// S[gt][pred] = gn - 2 p.g via mfma_f32_32x32x16_f16 with hi/lo split K-slots:
//  A kh0: [hux,huy,huz,hux,huy,huz,lux,luy]  A kh1: [luz,gnh,gnl,0,0,0,0,0]
//  B kh0: [hpx,hpy,hpz,lpx,lpy,lpz,hpx,hpy]  B kh1: [hpz,1,1,0,0,0,0,0]
// 16 KB LDS + ~56 VGPR + 32 AGPR -> 4 blocks/CU. NOTE: do NOT raise the
// launch_bounds occupancy request: (256,8) caps regs at 64/lane -> full
// accumulator spill -> 2 GB scratch traffic, 27x slower (R14 post-mortem).
__global__ __launch_bounds__(BLK, 4) void adds_mfma(
    const float* __restrict__ pred_R, const float* __restrict__ pred_t,
    const float* __restrict__ gt_R,   const float* __restrict__ gt_t,
    const float* __restrict__ mp,     float* __restrict__ pmin,
    float* __restrict__ out)
{
    __shared__ half8 aT[NT * 64];        // 16 KB, [tile][vlane]

    const int bid = blockIdx.x;
    const int gtq = bid & (GTQ - 1);
    const int pg  = (bid >> 3) & (PGRP - 1);
    const int b   = bid >> 6;
    const int tid = threadIdx.x;
    const int ln  = tid & 63;
    const int wv  = tid >> 6;

    if (bid == 0 && tid == 0) out[0] = 0.0f;   // re-zero every call (replay-safe)

    // ---- stage A tiles: 512 points, one transform per point, 2 entries ----
    {
        float gR[9];
#pragma unroll
        for (int i = 0; i < 9; ++i) gR[i] = gt_R[b * 9 + i];
        const float gtx = gt_t[b * 3 + 0];
        const float gty = gt_t[b * 3 + 1];
        const float gtz = gt_t[b * 3 + 2];

#pragma unroll
        for (int j = 0; j < GTN / BLK; ++j) {         // 2 points per thread
            const int nl = j * BLK + tid;             // 0..511
            const int n  = gtq * GTN + nl;
            const float mx = mp[n * 3 + 0];
            const float my = mp[n * 3 + 1];
            const float mz = mp[n * 3 + 2];
            const float gx = fmaf(gR[0], mx, fmaf(gR[1], my, fmaf(gR[2], mz, gtx)));
            const float gy = fmaf(gR[3], mx, fmaf(gR[4], my, fmaf(gR[5], mz, gty)));
            const float gz = fmaf(gR[6], mx, fmaf(gR[7], my, fmaf(gR[8], mz, gtz)));
            const float gn = fmaf(gx, gx, fmaf(gy, gy, gz * gz));
            const float ux = -2.0f * gx, uy = -2.0f * gy, uz = -2.0f * gz;
            _Float16 hux, lux, huy, luy, huz, luz, gnh, gnl;
            split16(ux, hux, lux);
            split16(uy, huy, luy);
            split16(uz, huz, luz);
            split16(gn, gnh, gnl);
            half8 k0, k1;
            k0[0] = hux; k0[1] = huy; k0[2] = huz;
            k0[3] = hux; k0[4] = huy; k0[5] = huz;
            k0[6] = lux; k0[7] = luy;
            k1[0] = luz; k1[1] = gnh; k1[2] = gnl;
            k1[3] = (_Float16)0.0f; k1[4] = (_Float16)0.0f; k1[5] = (_Float16)0.0f;
            k1[6] = (_Float16)0.0f; k1[7] = (_Float16)0.0f;
            const int t = nl >> 5, r = nl & 31;
            aT[t * 64 + r]      = k0;
            aT[t * 64 + 32 + r] = k1;
        }
    }

    // ---- B-fragments (pred side), constant across tiles ----
    float pR[9];
#pragma unroll
    for (int i = 0; i < 9; ++i) pR[i] = pred_R[b * 9 + i];
    const float ptx = pred_t[b * 3 + 0];
    const float pty = pred_t[b * 3 + 1];
    const float ptz = pred_t[b * 3 + 2];

    half8 bf[FRAGS];
    float pn[FRAGS];
    const int kh = ln >> 5;
#pragma unroll
    for (int f = 0; f < FRAGS; ++f) {
        const int predl = pg * PREDS_PER_BLK + wv * 128 + f * 32 + (ln & 31);
        const float mx = mp[predl * 3 + 0];
        const float my = mp[predl * 3 + 1];
        const float mz = mp[predl * 3 + 2];
        const float px = fmaf(pR[0], mx, fmaf(pR[1], my, fmaf(pR[2], mz, ptx)));
        const float py = fmaf(pR[3], mx, fmaf(pR[4], my, fmaf(pR[5], mz, pty)));
        const float pz = fmaf(pR[6], mx, fmaf(pR[7], my, fmaf(pR[8], mz, ptz)));
        pn[f] = fmaf(px, px, fmaf(py, py, pz * pz));
        _Float16 hpx, lpx, hpy, lpy, hpz, lpz;
        split16(px, hpx, lpx);
        split16(py, hpy, lpy);
        split16(pz, hpz, lpz);
        half8 v;
        if (kh == 0) {
            v[0] = hpx; v[1] = hpy; v[2] = hpz;
            v[3] = lpx; v[4] = lpy; v[5] = lpz;
            v[6] = hpx; v[7] = hpy;
        } else {
            v[0] = hpz; v[1] = (_Float16)1.0f; v[2] = (_Float16)1.0f;
            v[3] = (_Float16)0.0f; v[4] = (_Float16)0.0f;
            v[5] = (_Float16)0.0f; v[6] = (_Float16)0.0f;
            v[7] = (_Float16)0.0f;
        }
        bf[f] = v;
    }

    __syncthreads();

    // ---- MFMA loop over 16 gt tiles (2+2 MFMA groups) ----
    f32x16 zc;
#pragma unroll
    for (int i = 0; i < 16; ++i) zc[i] = 0.0f;

    float best[FRAGS][8];
#pragma unroll
    for (int f = 0; f < FRAGS; ++f)
#pragma unroll
        for (int j = 0; j < 8; ++j) best[f][j] = FLT_MAX;

    half8 a_cur = aT[ln];
    for (int t = 0; t < NT; ++t) {
        const half8 a_nxt = (t + 1 < NT) ? aT[(t + 1) * 64 + ln] : a_cur;
        {
            const f32x16 d0 = __builtin_amdgcn_mfma_f32_32x32x16_f16(a_cur, bf[0], zc, 0, 0, 0);
            const f32x16 d1 = __builtin_amdgcn_mfma_f32_32x32x16_f16(a_cur, bf[1], zc, 0, 0, 0);
#pragma unroll
            for (int j = 0; j < 8; ++j) {
                best[0][j] = fminf(best[0][j], fminf(d0[2 * j], d0[2 * j + 1]));
                best[1][j] = fminf(best[1][j], fminf(d1[2 * j], d1[2 * j + 1]));
            }
        }
        {
            const f32x16 d2 = __builtin_amdgcn_mfma_f32_32x32x16_f16(a_cur, bf[2], zc, 0, 0, 0);
            const f32x16 d3 = __builtin_amdgcn_mfma_f32_32x32x16_f16(a_cur, bf[3], zc, 0, 0, 0);
#pragma unroll
            for (int j = 0; j < 8; ++j) {
                best[2][j] = fminf(best[2][j], fminf(d2[2 * j], d2[2 * j + 1]));
                best[3][j] = fminf(best[3][j], fminf(d3[2 * j], d3[2 * j + 1]));
            }
        }
        a_cur = a_nxt;
    }

    // ---- epilogue: fold 8 regs, merge lane halves, add pn, store ----
#pragma unroll
    for (int f = 0; f < FRAGS; ++f) {
        float r = fminf(fminf(fminf(best[f][0], best[f][1]), fminf(best[f][2], best[f][3])),
                        fminf(fminf(best[f][4], best[f][5]), fminf(best[f][6], best[f][7])));
        r = fminf(r, __shfl_xor(r, 32, 64));
        const float d2v = fmaxf(pn[f] + r, 0.0f);
        if (ln < 32) {
            const int predl = pg * PREDS_PER_BLK + wv * 128 + f * 32 + ln;
            pmin[gtq * NPRED + b * MPTS + predl] = d2v;
        }
    }
}

// Finish: per pred point min over the 8 partials -> sqrt -> block sum ->
// atomicAdd of the scaled partial into out[0] (zeroed by adds_mfma).
__global__ __launch_bounds__(512) void adds_finish(
    const float* __restrict__ pmin, float* __restrict__ out)
{
    __shared__ float wsum[8];
    const int tid = threadIdx.x;
    const int g = blockIdx.x * 512 + tid;
    float m0 = FLT_MAX, m1 = FLT_MAX;
#pragma unroll
    for (int q = 0; q < GTQ; q += 2) {
        m0 = fminf(m0, pmin[(q + 0) * NPRED + g]);
        m1 = fminf(m1, pmin[(q + 1) * NPRED + g]);
    }
    float s = sqrtf(fminf(m0, m1));
#pragma unroll
    for (int off = 32; off > 0; off >>= 1) s += __shfl_down(s, off, 64);
    if ((tid & 63) == 0) wsum[tid >> 6] = s;
    __syncthreads();
    if (tid == 0) {
        float t = 0.0f;
#pragma unroll
        for (int w = 0; w < 8; ++w) t += wsum[w];
        atomicAdd(out, t * (1.0f / (float)NPRED));
    }
}

extern "C" void kernel_launch(void* const* d_in, const int* in_sizes, int n_in,
                              void* d_out, int out_size, void* d_ws, size_t ws_size,
                              hipStream_t stream) {
    const float* pred_R = (const float*)d_in[0];
    const float* pred_t = (const float*)d_in[1];
    const float* gt_R   = (const float*)d_in[2];
    const float* gt_t   = (const float*)d_in[3];
    const float* mp     = (const float*)d_in[4];
    float* out = (float*)d_out;
    float* pmin = (float*)d_ws;                 // 8*64K*4 = 2 MB

    // grid: b(16) x pred-group(8) x gtq(8) = 1024 blocks (4 blocks/CU)
    adds_mfma<<<dim3(NB * PGRP * GTQ), dim3(BLK), 0, stream>>>(
        pred_R, pred_t, gt_R, gt_t, mp, pmin, out);
    adds_finish<<<dim3(NPRED / 512), dim3(512), 0, stream>>>(pmin, out);
}